// Round 10
// baseline (180.770 us; speedup 1.0000x reference)
//
#include <hip/hip_runtime.h>
#include <hip/hip_bf16.h>

typedef unsigned short u16;
typedef __attribute__((ext_vector_type(8))) short short8v;   // 8 bf16 = 16B
typedef __attribute__((ext_vector_type(4))) float f32x4;

__device__ inline u16 f2b(float f) {
    __hip_bfloat16 h = __float2bfloat16(f);
    u16 u; __builtin_memcpy(&u, &h, 2); return u;
}
__device__ inline float b2f(u16 u) {
    __hip_bfloat16 h; __builtin_memcpy(&h, &u, 2); return __bfloat162float(h);
}
// load 8 contiguous fp32, round to 8 bf16
__device__ inline short8v cvt8(const float* p) {
    const f32x4 a = *(const f32x4*)p;
    const f32x4 b = *(const f32x4*)(p + 4);
    short8v s;
    #pragma unroll
    for (int e = 0; e < 4; ++e) { s[e] = (short)f2b(a[e]); s[4 + e] = (short)f2b(b[e]); }
    return s;
}

// ---------------------------------------------------------------------------
// x -> bf16 converter (one pass; ~24MB traffic)
// ---------------------------------------------------------------------------
__global__ __launch_bounds__(256) void convx_kernel(
    const float* __restrict__ src, u16* __restrict__ dst, int n8)
{
    const int i = blockIdx.x * 256 + threadIdx.x;
    if (i < n8) *(short8v*)&dst[(size_t)i * 8] = cvt8(src + (size_t)i * 8);
}

// ---------------------------------------------------------------------------
// Mixed-staging GEMM: C[m][n] = sum_k A[m][k]*B[n][k] + bias[n], fp32 accum.
// A: bf16, staged via global_load_lds width=16 into LINEAR As[128][32]
//    (wave-uniform LDS base + per-lane global addr — m104 contract).
// B: fp32 weights, cvt8 reg-staged into padded Bs[128][40].
// 128x128 tile, BK=32, 256 thr (4 waves 2x2, 64x64 each, 4x4 frags).
// ---------------------------------------------------------------------------
template<int OF32>
__global__ __launch_bounds__(256, 2) void gemm_bt_mixed(
    const u16* __restrict__ Ap, const float* __restrict__ Bw,
    const float* __restrict__ bias, void* __restrict__ Cp,
    int M, int N, int K)
{
    __shared__ __align__(16) u16 As[128 * 32];   // linear: gload_lds dest
    __shared__ __align__(16) u16 Bs[128 * 40];   // padded: reg-staged
    const int tid  = threadIdx.x;
    const int wave = tid >> 6, lane = tid & 63;
    const int l15  = lane & 15, l4 = lane >> 4;
    const int row0 = blockIdx.x * 128, col0 = blockIdx.y * 128;
    const int wm = (wave >> 1) * 64, wn = (wave & 1) * 64;

    f32x4 acc[4][4];
    #pragma unroll
    for (int i = 0; i < 4; ++i)
        #pragma unroll
        for (int j = 0; j < 4; ++j) acc[i][j] = (f32x4)0.f;

    const int sr = tid >> 2, sc = tid & 3;       // B stage: row, 16B chunk
    const int ar = lane >> 2, ac = lane & 3;     // A stage: per-lane row/chunk

    for (int kt = 0; kt < K; kt += 32) {
        // B -> regs early (latency hides under prev MFMA + barrier)
        short8v vb[2];
        #pragma unroll
        for (int it = 0; it < 2; ++it) {
            const int r = sr + it * 64;
            vb[it] = cvt8(Bw + (size_t)(col0 + r) * K + kt + sc * 8);
        }
        __syncthreads();                         // prev tile LDS reads done
        // A: async global->LDS, 2 issues/thread, 1KB/wave-issue
        #pragma unroll
        for (int i = 0; i < 2; ++i) {
            const int arow = wave * 32 + i * 16 + ar;
            const u16* ga = Ap + (size_t)(row0 + arow) * K + kt + ac * 8;
            u16* lb = &As[(wave * 32 + i * 16) * 32];   // wave-uniform base
            __builtin_amdgcn_global_load_lds(
                (const __attribute__((address_space(1))) unsigned int*)ga,
                (__attribute__((address_space(3))) unsigned int*)lb, 16, 0, 0);
        }
        // B -> LDS
        #pragma unroll
        for (int it = 0; it < 2; ++it) {
            const int r = sr + it * 64;
            *(short8v*)&Bs[r * 40 + sc * 8] = vb[it];
        }
        __syncthreads();                         // drains vmcnt+lgkm

        short8v af[4], bf[4];
        #pragma unroll
        for (int i = 0; i < 4; ++i) {
            af[i] = *(const short8v*)&As[(wm + i * 16 + l15) * 32 + l4 * 8];
            bf[i] = *(const short8v*)&Bs[(wn + i * 16 + l15) * 40 + l4 * 8];
        }
        #pragma unroll
        for (int i = 0; i < 4; ++i)
            #pragma unroll
            for (int j = 0; j < 4; ++j)
                acc[i][j] = __builtin_amdgcn_mfma_f32_16x16x32_bf16(af[i], bf[j], acc[i][j], 0, 0, 0);
    }

    // epilogue: D layout col=lane&15, row=(lane>>4)*4+reg
    #pragma unroll
    for (int i = 0; i < 4; ++i) {
        const int r = row0 + wm + i * 16 + l4 * 4;
        #pragma unroll
        for (int j = 0; j < 4; ++j) {
            const int c = col0 + wn + j * 16 + l15;
            const float bv = bias[c];
            #pragma unroll
            for (int reg = 0; reg < 4; ++reg) {
                const float rv = acc[i][j][reg] + bv;
                if (OF32) ((float*)Cp)[(size_t)(r + reg) * N + c] = rv;
                else      ((u16*)Cp)[(size_t)(r + reg) * N + c]   = f2b(rv);
            }
        }
    }
}

// ---------------------------------------------------------------------------
// V transpose: VT[bi][hi][d][n] = V[bi][n][hi*64+d]  (V = KVb cols 1024..2047)
// ---------------------------------------------------------------------------
__global__ __launch_bounds__(256) void vtrans_kernel(
    const u16* __restrict__ KVb, u16* __restrict__ VT)
{
    const int u    = blockIdx.x * 4 + (threadIdx.x >> 6);
    const int lane = threadIdx.x & 63;
    const int nch  = u & 255;            // 256 chunks of 8 n
    const int hi   = (u >> 8) & 15;
    const int bi   = u >> 12;
    const int n0   = nch * 8;

    short8v sv;
    #pragma unroll
    for (int i = 0; i < 8; ++i)
        sv[i] = (short)KVb[((size_t)(bi * 2048 + n0 + i)) * 2048 + 1024 + hi * 64 + lane];
    *(short8v*)&VT[((size_t)((bi * 16 + hi) * 64 + lane)) * 2048 + n0] = sv;
}

// ---------------------------------------------------------------------------
// Flash attention (causal) — unchanged from round 9 (proven).
// KVBLK=64; causal-paired q-tiles (p, 31-p); 4 waves; V from VT.
// ---------------------------------------------------------------------------
#define ATT_N 2048
#define ATT_D 1024
#define ATT_HD 64

__global__ __launch_bounds__(256, 2) void flash_attn_kernel(
    const u16* __restrict__ Q, const u16* __restrict__ KV,
    const u16* __restrict__ VT, u16* __restrict__ AO)
{
    const int tid  = threadIdx.x;
    const int wave = tid >> 6, lane = tid & 63;
    const int l15  = lane & 15, l4 = lane >> 4;
    const int pidx = blockIdx.x, hi = blockIdx.y, bi = blockIdx.z;

    __shared__ __align__(16) u16 Ks[64 * 72];
    __shared__ __align__(16) u16 Vs[64 * 72];
    __shared__ __align__(16) u16 Ps[4][16 * 72];

    const int sr = tid >> 2, sc = tid & 3;
    const size_t kv_base = (size_t)bi * ATT_N * 2048;
    const size_t vt_base = ((size_t)(bi * 16 + hi)) * 64 * ATT_N;

    for (int ph = 0; ph < 2; ++ph) {
        const int qt  = ph ? (31 - pidx) : pidx;
        const int q0  = qt * 64;
        const int qr0 = q0 + wave * 16;

        const u16* qp = Q + ((size_t)(bi * ATT_N + qr0 + l15)) * ATT_D + hi * ATT_HD;
        const short8v aq0 = *(const short8v*)(qp + l4 * 8);
        const short8v aq1 = *(const short8v*)(qp + 32 + l4 * 8);

        float mrow[4], lrow[4];
        f32x4 oacc[4];
        #pragma unroll
        for (int r = 0; r < 4; ++r) { mrow[r] = -1e30f; lrow[r] = 0.f; oacc[r] = (f32x4)0.f; }

        const int nt = qt + 1;
        for (int t = 0; t < nt; ++t) {
            const int kv0 = t * 64;
            const u16* gk = KV + kv_base + (size_t)(kv0 + sr) * 2048 + hi * ATT_HD + sc * 16;
            const u16* gv = VT + vt_base + (size_t)sr * ATT_N + kv0 + sc * 16;
            const short8v k0 = *(const short8v*)gk;
            const short8v k1 = *(const short8v*)(gk + 8);
            const short8v v0 = *(const short8v*)gv;
            const short8v v1 = *(const short8v*)(gv + 8);
            __syncthreads();
            *(short8v*)&Ks[sr * 72 + sc * 16]     = k0;
            *(short8v*)&Ks[sr * 72 + sc * 16 + 8] = k1;
            *(short8v*)&Vs[sr * 72 + sc * 16]     = v0;
            *(short8v*)&Vs[sr * 72 + sc * 16 + 8] = v1;
            __syncthreads();

            f32x4 s[4];
            #pragma unroll
            for (int tt = 0; tt < 4; ++tt) {
                s[tt] = (f32x4)0.f;
                const int rb = tt * 16 + l15;
                const short8v bk0 = *(const short8v*)&Ks[rb * 72 + l4 * 8];
                const short8v bk1 = *(const short8v*)&Ks[rb * 72 + 32 + l4 * 8];
                s[tt] = __builtin_amdgcn_mfma_f32_16x16x32_bf16(aq0, bk0, s[tt], 0, 0, 0);
                s[tt] = __builtin_amdgcn_mfma_f32_16x16x32_bf16(aq1, bk1, s[tt], 0, 0, 0);
            }
            float pv[4][4];
            #pragma unroll
            for (int tt = 0; tt < 4; ++tt)
                #pragma unroll
                for (int r = 0; r < 4; ++r) {
                    const int qg = qr0 + l4 * 4 + r;
                    const int kg = kv0 + tt * 16 + l15;
                    pv[tt][r] = (kg <= qg) ? s[tt][r] * 0.125f : -1e30f;
                }
            #pragma unroll
            for (int r = 0; r < 4; ++r) {
                float v = fmaxf(fmaxf(pv[0][r], pv[1][r]), fmaxf(pv[2][r], pv[3][r]));
                #pragma unroll
                for (int off = 1; off < 16; off <<= 1)
                    v = fmaxf(v, __shfl_xor(v, off, 64));
                const float mnew = fmaxf(mrow[r], v);
                const float sf = __expf(mrow[r] - mnew);
                mrow[r] = mnew;
                lrow[r] *= sf;
                #pragma unroll
                for (int j = 0; j < 4; ++j) oacc[j][r] *= sf;
                float sum = 0.f;
                #pragma unroll
                for (int tt = 0; tt < 4; ++tt) {
                    const float p = __expf(pv[tt][r] - mnew);
                    pv[tt][r] = p;
                    sum += p;
                }
                #pragma unroll
                for (int off = 1; off < 16; off <<= 1)
                    sum += __shfl_xor(sum, off, 64);
                lrow[r] += sum;
            }
            u16* Pw = &Ps[wave][0];
            #pragma unroll
            for (int tt = 0; tt < 4; ++tt)
                #pragma unroll
                for (int r = 0; r < 4; ++r)
                    Pw[(l4 * 4 + r) * 72 + tt * 16 + l15] = f2b(pv[tt][r]);
            const short8v ap0 = *(const short8v*)&Pw[l15 * 72 + l4 * 8];
            const short8v ap1 = *(const short8v*)&Pw[l15 * 72 + 32 + l4 * 8];
            #pragma unroll
            for (int j = 0; j < 4; ++j) {
                const int rb = j * 16 + l15;
                const short8v bv0 = *(const short8v*)&Vs[rb * 72 + l4 * 8];
                const short8v bv1 = *(const short8v*)&Vs[rb * 72 + 32 + l4 * 8];
                oacc[j] = __builtin_amdgcn_mfma_f32_16x16x32_bf16(ap0, bv0, oacc[j], 0, 0, 0);
                oacc[j] = __builtin_amdgcn_mfma_f32_16x16x32_bf16(ap1, bv1, oacc[j], 0, 0, 0);
            }
        }

        u16* op = AO + ((size_t)(bi * ATT_N + qr0)) * ATT_D + hi * ATT_HD;
        #pragma unroll
        for (int j = 0; j < 4; ++j)
            #pragma unroll
            for (int r = 0; r < 4; ++r)
                op[(size_t)(l4 * 4 + r) * ATT_D + j * 16 + l15] = f2b(oacc[j][r] / lrow[r]);
    }
}

// ---------------------------------------------------------------------------
extern "C" void kernel_launch(void* const* d_in, const int* in_sizes, int n_in,
                              void* d_out, int out_size, void* d_ws, size_t ws_size,
                              hipStream_t stream) {
    const float* x   = (const float*)d_in[0];
    const float* Wq  = (const float*)d_in[1];
    const float* bq  = (const float*)d_in[2];
    const float* Wkv = (const float*)d_in[3];
    const float* bkv = (const float*)d_in[4];
    const float* Wo  = (const float*)d_in[5];
    const float* bo  = (const float*)d_in[6];
    float* out = (float*)d_out;

    // ws layout (40MB total, <= 42.2MB proven):
    u16* xb  = (u16*)d_ws;                    // 4096x1024 bf16 (8MB); reused as AOb
    u16* Qb  = xb  + (size_t)4096 * 1024;     // 4096x1024 bf16 (8MB)
    u16* KVb = Qb  + (size_t)4096 * 1024;     // 4096x2048 bf16 (16MB)
    u16* VTb = KVb + (size_t)4096 * 2048;     // [2][16][64][2048] (8MB)
    u16* AOb = xb;                            // xb dead after kvproj

    dim3 blk(256);
    convx_kernel<<<dim3(2048), blk, 0, stream>>>(x, xb, 4096 * 1024 / 8);
    gemm_bt_mixed<0><<<dim3(32,  8), blk, 0, stream>>>(xb,  Wq,  bq,  Qb,  4096, 1024, 1024);
    gemm_bt_mixed<0><<<dim3(32, 16), blk, 0, stream>>>(xb,  Wkv, bkv, KVb, 4096, 2048, 1024);
    vtrans_kernel<<<dim3(2048), blk, 0, stream>>>(KVb, VTb);
    flash_attn_kernel<<<dim3(16, 16, 2), blk, 0, stream>>>(Qb, KVb, VTb, AOb);
    gemm_bt_mixed<1><<<dim3(32,  8), blk, 0, stream>>>(AOb, Wo,  bo,  out, 4096, 1024, 1024);
}

// Round 11
// 168.940 us; speedup vs baseline: 1.0700x; 1.0700x over previous
//
#include <hip/hip_runtime.h>
#include <hip/hip_bf16.h>

typedef unsigned short u16;
typedef __attribute__((ext_vector_type(8))) short short8v;   // 8 bf16 = 16B
typedef __attribute__((ext_vector_type(4))) float f32x4;

__device__ inline u16 f2b(float f) {
    __hip_bfloat16 h = __float2bfloat16(f);
    u16 u; __builtin_memcpy(&u, &h, 2); return u;
}
__device__ inline float b2f(u16 u) {
    __hip_bfloat16 h; __builtin_memcpy(&h, &u, 2); return __bfloat162float(h);
}
__device__ inline short8v cvt8(const float* p) {
    const f32x4 a = *(const f32x4*)p;
    const f32x4 b = *(const f32x4*)(p + 4);
    short8v s;
    #pragma unroll
    for (int e = 0; e < 4; ++e) { s[e] = (short)f2b(a[e]); s[4 + e] = (short)f2b(b[e]); }
    return s;
}

// ---------------------------------------------------------------------------
// fp32 -> bf16 converter (grid-stride free; exact-sized grids used)
// ---------------------------------------------------------------------------
__global__ __launch_bounds__(256) void convx_kernel(
    const float* __restrict__ src, u16* __restrict__ dst, int n8)
{
    const int i = blockIdx.x * 256 + threadIdx.x;
    if (i < n8) *(short8v*)&dst[(size_t)i * 8] = cvt8(src + (size_t)i * 8);
}

// ---------------------------------------------------------------------------
// Pure-bf16 GEMM (m97 structure): C[m][n] = sum_k A[m][k]*B[n][k] + bias[n].
// A,B bf16 staged via global_load_lds width=16 into linear [128][32] LDS;
// zero staging VALU in the K-loop. 128x128 tile, BK=32, 256 thr, 4x4 frags.
// ---------------------------------------------------------------------------
template<int OF32>
__global__ __launch_bounds__(256, 2) void gemm_bt16(
    const u16* __restrict__ Ap, const u16* __restrict__ Bw,
    const float* __restrict__ bias, void* __restrict__ Cp,
    int M, int N, int K)
{
    __shared__ __align__(16) u16 As[128 * 32];
    __shared__ __align__(16) u16 Bs[128 * 32];
    const int tid  = threadIdx.x;
    const int wave = tid >> 6, lane = tid & 63;
    const int l15  = lane & 15, l4 = lane >> 4;
    const int row0 = blockIdx.x * 128, col0 = blockIdx.y * 128;
    const int wm = (wave >> 1) * 64, wn = (wave & 1) * 64;

    f32x4 acc[4][4];
    #pragma unroll
    for (int i = 0; i < 4; ++i)
        #pragma unroll
        for (int j = 0; j < 4; ++j) acc[i][j] = (f32x4)0.f;

    const int ar = lane >> 2, ac = lane & 3;   // per-lane row/16B-chunk in a 16-row slab

    for (int kt = 0; kt < K; kt += 32) {
        __syncthreads();                       // prev tile's LDS reads complete
        #pragma unroll
        for (int i = 0; i < 2; ++i) {
            const int slab = wave * 32 + i * 16;         // 16 rows per issue
            const u16* ga = Ap + (size_t)(row0 + slab + ar) * K + kt + ac * 8;
            const u16* gb = Bw + (size_t)(col0 + slab + ar) * K + kt + ac * 8;
            __builtin_amdgcn_global_load_lds(
                (const __attribute__((address_space(1))) unsigned int*)ga,
                (__attribute__((address_space(3))) unsigned int*)&As[slab * 32], 16, 0, 0);
            __builtin_amdgcn_global_load_lds(
                (const __attribute__((address_space(1))) unsigned int*)gb,
                (__attribute__((address_space(3))) unsigned int*)&Bs[slab * 32], 16, 0, 0);
        }
        __syncthreads();                       // drains vmcnt -> LDS ready

        short8v af[4], bf[4];
        #pragma unroll
        for (int i = 0; i < 4; ++i) {
            af[i] = *(const short8v*)&As[(wm + i * 16 + l15) * 32 + l4 * 8];
            bf[i] = *(const short8v*)&Bs[(wn + i * 16 + l15) * 32 + l4 * 8];
        }
        #pragma unroll
        for (int i = 0; i < 4; ++i)
            #pragma unroll
            for (int j = 0; j < 4; ++j)
                acc[i][j] = __builtin_amdgcn_mfma_f32_16x16x32_bf16(af[i], bf[j], acc[i][j], 0, 0, 0);
    }

    #pragma unroll
    for (int i = 0; i < 4; ++i) {
        const int r = row0 + wm + i * 16 + l4 * 4;
        #pragma unroll
        for (int j = 0; j < 4; ++j) {
            const int c = col0 + wn + j * 16 + l15;
            const float bv = bias[c];
            #pragma unroll
            for (int reg = 0; reg < 4; ++reg) {
                const float rv = acc[i][j][reg] + bv;
                if (OF32) ((float*)Cp)[(size_t)(r + reg) * N + c] = rv;
                else      ((u16*)Cp)[(size_t)(r + reg) * N + c]   = f2b(rv);
            }
        }
    }
}

// ---------------------------------------------------------------------------
// V transpose: VT[bi][hi][d][n] = V[bi][n][hi*64+d]  (V = KVb cols 1024..2047)
// ---------------------------------------------------------------------------
__global__ __launch_bounds__(256) void vtrans_kernel(
    const u16* __restrict__ KVb, u16* __restrict__ VT)
{
    const int u    = blockIdx.x * 4 + (threadIdx.x >> 6);
    const int lane = threadIdx.x & 63;
    const int nch  = u & 255;
    const int hi   = (u >> 8) & 15;
    const int bi   = u >> 12;
    const int n0   = nch * 8;

    short8v sv;
    #pragma unroll
    for (int i = 0; i < 8; ++i)
        sv[i] = (short)KVb[((size_t)(bi * 2048 + n0 + i)) * 2048 + 1024 + hi * 64 + lane];
    *(short8v*)&VT[((size_t)((bi * 16 + hi) * 64 + lane)) * 2048 + n0] = sv;
}

// ---------------------------------------------------------------------------
// Flash attention (causal), 8-wave paired blocks: waves 0-3 own q-tile
// (31-pidx), waves 4-7 own q-tile pidx; ONE shared K/V staging loop over the
// longer range. Per-wave math identical to round-9 (proven). 512 thr/block.
// ---------------------------------------------------------------------------
#define ATT_N 2048
#define ATT_D 1024
#define ATT_HD 64

__global__ __launch_bounds__(512, 2) void flash_attn_kernel(
    const u16* __restrict__ Q, const u16* __restrict__ KV,
    const u16* __restrict__ VT, u16* __restrict__ AO)
{
    const int tid  = threadIdx.x;
    const int wave = tid >> 6, lane = tid & 63;
    const int l15  = lane & 15, l4 = lane >> 4;
    const int pidx = blockIdx.x, hi = blockIdx.y, bi = blockIdx.z;
    const int grp  = wave >> 2, wq = wave & 3;

    const int qt  = grp ? pidx : (31 - pidx);
    const int nt  = qt + 1;                    // tiles this group computes
    const int ntmax = 32 - pidx;               // staged iterations (long tile)
    const int qr0 = qt * 64 + wq * 16;

    __shared__ __align__(16) u16 Ks[64 * 72];
    __shared__ __align__(16) u16 Vs[64 * 72];
    __shared__ __align__(16) u16 Ps[8][16 * 72];

    const int sr = tid >> 3, sc = tid & 7;     // 64 rows x 8 chunks of 16B
    const size_t kv_base = (size_t)bi * ATT_N * 2048;
    const size_t vt_base = ((size_t)(bi * 16 + hi)) * 64 * ATT_N;

    const u16* qp = Q + ((size_t)(bi * ATT_N + qr0 + l15)) * ATT_D + hi * ATT_HD;
    const short8v aq0 = *(const short8v*)(qp + l4 * 8);
    const short8v aq1 = *(const short8v*)(qp + 32 + l4 * 8);

    float mrow[4], lrow[4];
    f32x4 oacc[4];
    #pragma unroll
    for (int r = 0; r < 4; ++r) { mrow[r] = -1e30f; lrow[r] = 0.f; oacc[r] = (f32x4)0.f; }

    for (int t = 0; t < ntmax; ++t) {
        const int kv0 = t * 64;
        const u16* gk = KV + kv_base + (size_t)(kv0 + sr) * 2048 + hi * ATT_HD + sc * 8;
        const u16* gv = VT + vt_base + (size_t)sr * ATT_N + kv0 + sc * 8;
        const short8v kv_ = *(const short8v*)gk;
        const short8v vv_ = *(const short8v*)gv;
        __syncthreads();                       // prev tile LDS reads done
        *(short8v*)&Ks[sr * 72 + sc * 8] = kv_;
        *(short8v*)&Vs[sr * 72 + sc * 8] = vv_;
        __syncthreads();

        if (t < nt) {                          // group-uniform guard (no barriers inside)
            f32x4 s[4];
            #pragma unroll
            for (int tt = 0; tt < 4; ++tt) {
                s[tt] = (f32x4)0.f;
                const int rb = tt * 16 + l15;
                const short8v bk0 = *(const short8v*)&Ks[rb * 72 + l4 * 8];
                const short8v bk1 = *(const short8v*)&Ks[rb * 72 + 32 + l4 * 8];
                s[tt] = __builtin_amdgcn_mfma_f32_16x16x32_bf16(aq0, bk0, s[tt], 0, 0, 0);
                s[tt] = __builtin_amdgcn_mfma_f32_16x16x32_bf16(aq1, bk1, s[tt], 0, 0, 0);
            }
            float pv[4][4];
            #pragma unroll
            for (int tt = 0; tt < 4; ++tt)
                #pragma unroll
                for (int r = 0; r < 4; ++r) {
                    const int qg = qr0 + l4 * 4 + r;
                    const int kg = kv0 + tt * 16 + l15;
                    pv[tt][r] = (kg <= qg) ? s[tt][r] * 0.125f : -1e30f;
                }
            #pragma unroll
            for (int r = 0; r < 4; ++r) {
                float v = fmaxf(fmaxf(pv[0][r], pv[1][r]), fmaxf(pv[2][r], pv[3][r]));
                #pragma unroll
                for (int off = 1; off < 16; off <<= 1)
                    v = fmaxf(v, __shfl_xor(v, off, 64));
                const float mnew = fmaxf(mrow[r], v);
                const float sf = __expf(mrow[r] - mnew);
                mrow[r] = mnew;
                lrow[r] *= sf;
                #pragma unroll
                for (int j = 0; j < 4; ++j) oacc[j][r] *= sf;
                float sum = 0.f;
                #pragma unroll
                for (int tt = 0; tt < 4; ++tt) {
                    const float p = __expf(pv[tt][r] - mnew);
                    pv[tt][r] = p;
                    sum += p;
                }
                #pragma unroll
                for (int off = 1; off < 16; off <<= 1)
                    sum += __shfl_xor(sum, off, 64);
                lrow[r] += sum;
            }
            u16* Pw = &Ps[wave][0];
            #pragma unroll
            for (int tt = 0; tt < 4; ++tt)
                #pragma unroll
                for (int r = 0; r < 4; ++r)
                    Pw[(l4 * 4 + r) * 72 + tt * 16 + l15] = f2b(pv[tt][r]);
            const short8v ap0 = *(const short8v*)&Pw[l15 * 72 + l4 * 8];
            const short8v ap1 = *(const short8v*)&Pw[l15 * 72 + 32 + l4 * 8];
            #pragma unroll
            for (int j = 0; j < 4; ++j) {
                const int rb = j * 16 + l15;
                const short8v bv0 = *(const short8v*)&Vs[rb * 72 + l4 * 8];
                const short8v bv1 = *(const short8v*)&Vs[rb * 72 + 32 + l4 * 8];
                oacc[j] = __builtin_amdgcn_mfma_f32_16x16x32_bf16(ap0, bv0, oacc[j], 0, 0, 0);
                oacc[j] = __builtin_amdgcn_mfma_f32_16x16x32_bf16(ap1, bv1, oacc[j], 0, 0, 0);
            }
        }
    }

    u16* op = AO + ((size_t)(bi * ATT_N + qr0)) * ATT_D + hi * ATT_HD;
    #pragma unroll
    for (int j = 0; j < 4; ++j)
        #pragma unroll
        for (int r = 0; r < 4; ++r)
            op[(size_t)(l4 * 4 + r) * ATT_D + j * 16 + l15] = f2b(oacc[j][r] / lrow[r]);
}

// ---------------------------------------------------------------------------
extern "C" void kernel_launch(void* const* d_in, const int* in_sizes, int n_in,
                              void* d_out, int out_size, void* d_ws, size_t ws_size,
                              hipStream_t stream) {
    const float* x   = (const float*)d_in[0];
    const float* Wq  = (const float*)d_in[1];
    const float* bq  = (const float*)d_in[2];
    const float* Wkv = (const float*)d_in[3];
    const float* bkv = (const float*)d_in[4];
    const float* Wo  = (const float*)d_in[5];
    const float* bo  = (const float*)d_in[6];
    float* out = (float*)d_out;

    // ws layout: 40MB total (proven). Overlays:
    //   Wqb/Wkvb live in the VT region (dead before vtrans writes it);
    //   Wob lives in Qb (converted after flash, before outproj); AOb = xb.
    u16* xb   = (u16*)d_ws;                       // 8MB
    u16* Qb   = xb  + (size_t)4096 * 1024;        // 8MB
    u16* KVb  = Qb  + (size_t)4096 * 1024;        // 16MB
    u16* VTb  = KVb + (size_t)4096 * 2048;        // 8MB
    u16* Wqb  = VTb;                              // 2MB  (overlay)
    u16* Wkvb = VTb + (size_t)1024 * 1024;        // 4MB  (overlay)
    u16* Wob  = Qb;                               // 2MB  (overlay, post-flash)
    u16* AOb  = xb;

    dim3 blk(256);
    convx_kernel<<<dim3(2048), blk, 0, stream>>>(x,   xb,   4096 * 1024 / 8);
    convx_kernel<<<dim3( 512), blk, 0, stream>>>(Wq,  Wqb,  1024 * 1024 / 8);
    convx_kernel<<<dim3(1024), blk, 0, stream>>>(Wkv, Wkvb, 2048 * 1024 / 8);
    gemm_bt16<0><<<dim3(32,  8), blk, 0, stream>>>(xb, Wqb,  bq,  Qb,  4096, 1024, 1024);
    gemm_bt16<0><<<dim3(32, 16), blk, 0, stream>>>(xb, Wkvb, bkv, KVb, 4096, 2048, 1024);
    vtrans_kernel<<<dim3(2048), blk, 0, stream>>>(KVb, VTb);
    flash_attn_kernel<<<dim3(16, 16, 2), dim3(512), 0, stream>>>(Qb, KVb, VTb, AOb);
    convx_kernel<<<dim3( 512), blk, 0, stream>>>(Wo, Wob, 1024 * 1024 / 8);
    gemm_bt16<1><<<dim3(32,  8), blk, 0, stream>>>(AOb, Wob, bo, out, 4096, 1024, 1024);
}

// Round 12
// 141.977 us; speedup vs baseline: 1.2732x; 1.1899x over previous
//
#include <hip/hip_runtime.h>
#include <hip/hip_bf16.h>

typedef unsigned short u16;
typedef __attribute__((ext_vector_type(8))) short short8v;   // 8 bf16 = 16B
typedef __attribute__((ext_vector_type(4))) float f32x4;

__device__ inline u16 f2b(float f) {
    __hip_bfloat16 h = __float2bfloat16(f);
    u16 u; __builtin_memcpy(&u, &h, 2); return u;
}
__device__ inline float b2f(u16 u) {
    __hip_bfloat16 h; __builtin_memcpy(&h, &u, 2); return __bfloat162float(h);
}
__device__ inline short8v cvt8(const float* p) {
    const f32x4 a = *(const f32x4*)p;
    const f32x4 b = *(const f32x4*)(p + 4);
    short8v s;
    #pragma unroll
    for (int e = 0; e < 4; ++e) { s[e] = (short)f2b(a[e]); s[4 + e] = (short)f2b(b[e]); }
    return s;
}

// DPP lane-permute within rows of 16 (reduction over lane&15):
//   0xB1 = quad_perm xor1, 0x4E = quad_perm xor2, 0x124 = row_ror:4, 0x128 = row_ror:8
template<int CTRL>
__device__ inline float dppf(float x) {
    return __int_as_float(__builtin_amdgcn_update_dpp(
        0, __float_as_int(x), CTRL, 0xF, 0xF, true));
}
__device__ inline float row16_max(float v) {
    v = fmaxf(v, dppf<0xB1>(v));
    v = fmaxf(v, dppf<0x4E>(v));
    v = fmaxf(v, dppf<0x124>(v));
    v = fmaxf(v, dppf<0x128>(v));
    return v;
}
__device__ inline float row16_sum(float v) {
    v += dppf<0xB1>(v);
    v += dppf<0x4E>(v);
    v += dppf<0x124>(v);
    v += dppf<0x128>(v);
    return v;
}

// ---------------------------------------------------------------------------
// fp32 -> bf16 converter
// ---------------------------------------------------------------------------
__global__ __launch_bounds__(256) void convx_kernel(
    const float* __restrict__ src, u16* __restrict__ dst, int n8)
{
    const int i = blockIdx.x * 256 + threadIdx.x;
    if (i < n8) *(short8v*)&dst[(size_t)i * 8] = cvt8(src + (size_t)i * 8);
}

// bias concat: dst[0..1023]=bq, dst[1024..3071]=bkv
__global__ __launch_bounds__(256) void bias_concat(
    const float* __restrict__ bq, const float* __restrict__ bkv,
    float* __restrict__ dst)
{
    const int i = blockIdx.x * 256 + threadIdx.x;
    if (i < 3072) dst[i] = (i < 1024) ? bq[i] : bkv[i - 1024];
}

// ---------------------------------------------------------------------------
// Pure-bf16 GEMM (m97 structure, round-11 proven): C = A @ B^T + bias.
// ---------------------------------------------------------------------------
template<int OF32>
__global__ __launch_bounds__(256, 2) void gemm_bt16(
    const u16* __restrict__ Ap, const u16* __restrict__ Bw,
    const float* __restrict__ bias, void* __restrict__ Cp,
    int M, int N, int K)
{
    __shared__ __align__(16) u16 As[128 * 32];
    __shared__ __align__(16) u16 Bs[128 * 32];
    const int tid  = threadIdx.x;
    const int wave = tid >> 6, lane = tid & 63;
    const int l15  = lane & 15, l4 = lane >> 4;
    const int row0 = blockIdx.x * 128, col0 = blockIdx.y * 128;
    const int wm = (wave >> 1) * 64, wn = (wave & 1) * 64;

    f32x4 acc[4][4];
    #pragma unroll
    for (int i = 0; i < 4; ++i)
        #pragma unroll
        for (int j = 0; j < 4; ++j) acc[i][j] = (f32x4)0.f;

    const int ar = lane >> 2, ac = lane & 3;

    for (int kt = 0; kt < K; kt += 32) {
        __syncthreads();
        #pragma unroll
        for (int i = 0; i < 2; ++i) {
            const int slab = wave * 32 + i * 16;
            const u16* ga = Ap + (size_t)(row0 + slab + ar) * K + kt + ac * 8;
            const u16* gb = Bw + (size_t)(col0 + slab + ar) * K + kt + ac * 8;
            __builtin_amdgcn_global_load_lds(
                (const __attribute__((address_space(1))) unsigned int*)ga,
                (__attribute__((address_space(3))) unsigned int*)&As[slab * 32], 16, 0, 0);
            __builtin_amdgcn_global_load_lds(
                (const __attribute__((address_space(1))) unsigned int*)gb,
                (__attribute__((address_space(3))) unsigned int*)&Bs[slab * 32], 16, 0, 0);
        }
        __syncthreads();

        short8v af[4], bf[4];
        #pragma unroll
        for (int i = 0; i < 4; ++i) {
            af[i] = *(const short8v*)&As[(wm + i * 16 + l15) * 32 + l4 * 8];
            bf[i] = *(const short8v*)&Bs[(wn + i * 16 + l15) * 32 + l4 * 8];
        }
        #pragma unroll
        for (int i = 0; i < 4; ++i)
            #pragma unroll
            for (int j = 0; j < 4; ++j)
                acc[i][j] = __builtin_amdgcn_mfma_f32_16x16x32_bf16(af[i], bf[j], acc[i][j], 0, 0, 0);
    }

    #pragma unroll
    for (int i = 0; i < 4; ++i) {
        const int r = row0 + wm + i * 16 + l4 * 4;
        #pragma unroll
        for (int j = 0; j < 4; ++j) {
            const int c = col0 + wn + j * 16 + l15;
            const float bv = bias[c];
            #pragma unroll
            for (int reg = 0; reg < 4; ++reg) {
                const float rv = acc[i][j][reg] + bv;
                if (OF32) ((float*)Cp)[(size_t)(r + reg) * N + c] = rv;
                else      ((u16*)Cp)[(size_t)(r + reg) * N + c]   = f2b(rv);
            }
        }
    }
}

// ---------------------------------------------------------------------------
// V transpose from fused QKV: VT[bi][hi][d][n] = QKV[bi][n][2048 + hi*64 + d]
// ---------------------------------------------------------------------------
#define QKV_LD 3072

__global__ __launch_bounds__(256) void vtrans_kernel(
    const u16* __restrict__ QKV, u16* __restrict__ VT)
{
    const int u    = blockIdx.x * 4 + (threadIdx.x >> 6);
    const int lane = threadIdx.x & 63;
    const int nch  = u & 255;
    const int hi   = (u >> 8) & 15;
    const int bi   = u >> 12;
    const int n0   = nch * 8;

    short8v sv;
    #pragma unroll
    for (int i = 0; i < 8; ++i)
        sv[i] = (short)QKV[((size_t)(bi * 2048 + n0 + i)) * QKV_LD + 2048 + hi * 64 + lane];
    *(short8v*)&VT[((size_t)((bi * 16 + hi) * 64 + lane)) * 2048 + n0] = sv;
}

// ---------------------------------------------------------------------------
// Flash attention (causal), 8-wave paired blocks (round-11 proven structure);
// Q,K from fused QKV (stride 3072); V from VT; DPP softmax reductions.
// ---------------------------------------------------------------------------
#define ATT_N 2048
#define ATT_D 1024
#define ATT_HD 64

__global__ __launch_bounds__(512, 2) void flash_attn_kernel(
    const u16* __restrict__ QKV, const u16* __restrict__ VT,
    u16* __restrict__ AO)
{
    const int tid  = threadIdx.x;
    const int wave = tid >> 6, lane = tid & 63;
    const int l15  = lane & 15, l4 = lane >> 4;
    const int pidx = blockIdx.x, hi = blockIdx.y, bi = blockIdx.z;
    const int grp  = wave >> 2, wq = wave & 3;

    const int qt  = grp ? pidx : (31 - pidx);
    const int nt  = qt + 1;
    const int ntmax = 32 - pidx;
    const int qr0 = qt * 64 + wq * 16;

    __shared__ __align__(16) u16 Ks[64 * 72];
    __shared__ __align__(16) u16 Vs[64 * 72];
    __shared__ __align__(16) u16 Ps[8][16 * 72];

    const int sr = tid >> 3, sc = tid & 7;
    const size_t kv_base = (size_t)bi * ATT_N * QKV_LD;
    const size_t vt_base = ((size_t)(bi * 16 + hi)) * 64 * ATT_N;

    const u16* qp = QKV + ((size_t)(bi * ATT_N + qr0 + l15)) * QKV_LD + hi * ATT_HD;
    const short8v aq0 = *(const short8v*)(qp + l4 * 8);
    const short8v aq1 = *(const short8v*)(qp + 32 + l4 * 8);

    float mrow[4], lrow[4];
    f32x4 oacc[4];
    #pragma unroll
    for (int r = 0; r < 4; ++r) { mrow[r] = -1e30f; lrow[r] = 0.f; oacc[r] = (f32x4)0.f; }

    for (int t = 0; t < ntmax; ++t) {
        const int kv0 = t * 64;
        const u16* gk = QKV + kv_base + (size_t)(kv0 + sr) * QKV_LD + 1024 + hi * ATT_HD + sc * 8;
        const u16* gv = VT + vt_base + (size_t)sr * ATT_N + kv0 + sc * 8;
        const short8v kv_ = *(const short8v*)gk;
        const short8v vv_ = *(const short8v*)gv;
        __syncthreads();
        *(short8v*)&Ks[sr * 72 + sc * 8] = kv_;
        *(short8v*)&Vs[sr * 72 + sc * 8] = vv_;
        __syncthreads();

        if (t < nt) {
            f32x4 s[4];
            #pragma unroll
            for (int tt = 0; tt < 4; ++tt) {
                s[tt] = (f32x4)0.f;
                const int rb = tt * 16 + l15;
                const short8v bk0 = *(const short8v*)&Ks[rb * 72 + l4 * 8];
                const short8v bk1 = *(const short8v*)&Ks[rb * 72 + 32 + l4 * 8];
                s[tt] = __builtin_amdgcn_mfma_f32_16x16x32_bf16(aq0, bk0, s[tt], 0, 0, 0);
                s[tt] = __builtin_amdgcn_mfma_f32_16x16x32_bf16(aq1, bk1, s[tt], 0, 0, 0);
            }
            float pv[4][4];
            #pragma unroll
            for (int tt = 0; tt < 4; ++tt)
                #pragma unroll
                for (int r = 0; r < 4; ++r) {
                    const int qg = qr0 + l4 * 4 + r;
                    const int kg = kv0 + tt * 16 + l15;
                    pv[tt][r] = (kg <= qg) ? s[tt][r] * 0.125f : -1e30f;
                }
            #pragma unroll
            for (int r = 0; r < 4; ++r) {
                float v = fmaxf(fmaxf(pv[0][r], pv[1][r]), fmaxf(pv[2][r], pv[3][r]));
                v = row16_max(v);                     // DPP, VALU-speed
                const float mnew = fmaxf(mrow[r], v);
                const float sf = __expf(mrow[r] - mnew);
                mrow[r] = mnew;
                lrow[r] *= sf;
                #pragma unroll
                for (int j = 0; j < 4; ++j) oacc[j][r] *= sf;
                float sum = 0.f;
                #pragma unroll
                for (int tt = 0; tt < 4; ++tt) {
                    const float p = __expf(pv[tt][r] - mnew);
                    pv[tt][r] = p;
                    sum += p;
                }
                sum = row16_sum(sum);                 // DPP, VALU-speed
                lrow[r] += sum;
            }
            u16* Pw = &Ps[wave][0];
            #pragma unroll
            for (int tt = 0; tt < 4; ++tt)
                #pragma unroll
                for (int r = 0; r < 4; ++r)
                    Pw[(l4 * 4 + r) * 72 + tt * 16 + l15] = f2b(pv[tt][r]);
            const short8v ap0 = *(const short8v*)&Pw[l15 * 72 + l4 * 8];
            const short8v ap1 = *(const short8v*)&Pw[l15 * 72 + 32 + l4 * 8];
            #pragma unroll
            for (int j = 0; j < 4; ++j) {
                const int rb = j * 16 + l15;
                const short8v bv0 = *(const short8v*)&Vs[rb * 72 + l4 * 8];
                const short8v bv1 = *(const short8v*)&Vs[rb * 72 + 32 + l4 * 8];
                oacc[j] = __builtin_amdgcn_mfma_f32_16x16x32_bf16(ap0, bv0, oacc[j], 0, 0, 0);
                oacc[j] = __builtin_amdgcn_mfma_f32_16x16x32_bf16(ap1, bv1, oacc[j], 0, 0, 0);
            }
        }
    }

    u16* op = AO + ((size_t)(bi * ATT_N + qr0)) * ATT_D + hi * ATT_HD;
    #pragma unroll
    for (int j = 0; j < 4; ++j)
        #pragma unroll
        for (int r = 0; r < 4; ++r)
            op[(size_t)(l4 * 4 + r) * ATT_D + j * 16 + l15] = f2b(oacc[j][r] / lrow[r]);
}

// ---------------------------------------------------------------------------
extern "C" void kernel_launch(void* const* d_in, const int* in_sizes, int n_in,
                              void* d_out, int out_size, void* d_ws, size_t ws_size,
                              hipStream_t stream) {
    const float* x   = (const float*)d_in[0];
    const float* Wq  = (const float*)d_in[1];
    const float* bq  = (const float*)d_in[2];
    const float* Wkv = (const float*)d_in[3];
    const float* bkv = (const float*)d_in[4];
    const float* Wo  = (const float*)d_in[5];
    const float* bo  = (const float*)d_in[6];
    float* out = (float*)d_out;

    // ws layout (40.01MB, <=42.2 proven):
    //   xb 8MB | QKVb 24MB | VTb 8MB | bqkv 12KB
    // overlays: Wqkvb = first 6MB of VTb (dead before vtrans writes VT);
    //           AOb = xb (dead after fused gemm); Wob = QKVb start (post-flash).
    u16* xb    = (u16*)d_ws;                        // 8MB
    u16* QKVb  = xb   + (size_t)4096 * 1024;        // 24MB  [4096][3072]
    u16* VTb   = QKVb + (size_t)4096 * 3072;        // 8MB
    float* bqkv = (float*)(VTb + (size_t)4096 * 2048);  // 12KB
    u16* Wqkvb = VTb;                               // 6MB overlay
    u16* Wob   = QKVb;                              // 2MB overlay (post-flash)
    u16* AOb   = xb;

    dim3 blk(256);
    convx_kernel<<<dim3(2048), blk, 0, stream>>>(x,   xb,    4096 * 1024 / 8);
    convx_kernel<<<dim3( 512), blk, 0, stream>>>(Wq,  Wqkvb, 1024 * 1024 / 8);
    convx_kernel<<<dim3(1024), blk, 0, stream>>>(Wkv, Wqkvb + (size_t)1024 * 1024, 2048 * 1024 / 8);
    bias_concat<<<dim3(12), blk, 0, stream>>>(bq, bkv, bqkv);
    gemm_bt16<0><<<dim3(32, 24), blk, 0, stream>>>(xb, Wqkvb, bqkv, QKVb, 4096, 3072, 1024);
    vtrans_kernel<<<dim3(2048), blk, 0, stream>>>(QKVb, VTb);
    flash_attn_kernel<<<dim3(16, 16, 2), dim3(512), 0, stream>>>(QKVb, VTb, AOb);
    convx_kernel<<<dim3( 512), blk, 0, stream>>>(Wo, Wob, 1024 * 1024 / 8);
    gemm_bt16<1><<<dim3(32, 8), blk, 0, stream>>>(AOb, Wob, bo, out, 4096, 1024, 1024);
}

// Round 13
// 135.495 us; speedup vs baseline: 1.3341x; 1.0478x over previous
//
#include <hip/hip_runtime.h>
#include <hip/hip_bf16.h>

typedef unsigned short u16;
typedef __attribute__((ext_vector_type(8))) short short8v;   // 8 bf16 = 16B
typedef __attribute__((ext_vector_type(4))) float f32x4;

__device__ inline u16 f2b(float f) {
    __hip_bfloat16 h = __float2bfloat16(f);
    u16 u; __builtin_memcpy(&u, &h, 2); return u;
}
__device__ inline float b2f(u16 u) {
    __hip_bfloat16 h; __builtin_memcpy(&h, &u, 2); return __bfloat162float(h);
}
__device__ inline short8v cvt8s(const float* p, float s) {
    const f32x4 a = *(const f32x4*)p;
    const f32x4 b = *(const f32x4*)(p + 4);
    short8v r;
    #pragma unroll
    for (int e = 0; e < 4; ++e) { r[e] = (short)f2b(a[e] * s); r[4 + e] = (short)f2b(b[e] * s); }
    return r;
}

// DPP lane-permute within rows of 16 (reduction over lane&15)
template<int CTRL>
__device__ inline float dppf(float x) {
    return __int_as_float(__builtin_amdgcn_update_dpp(
        0, __float_as_int(x), CTRL, 0xF, 0xF, true));
}
__device__ inline float row16_max(float v) {
    v = fmaxf(v, dppf<0xB1>(v));
    v = fmaxf(v, dppf<0x4E>(v));
    v = fmaxf(v, dppf<0x124>(v));
    v = fmaxf(v, dppf<0x128>(v));
    return v;
}
__device__ inline float row16_sum(float v) {
    v += dppf<0xB1>(v);
    v += dppf<0x4E>(v);
    v += dppf<0x124>(v);
    v += dppf<0x128>(v);
    return v;
}

// ---------------------------------------------------------------------------
// fp32 -> bf16 converter with fold-in scale (0.125 for Wq is exact in bf16)
// ---------------------------------------------------------------------------
__global__ __launch_bounds__(256) void convx_kernel(
    const float* __restrict__ src, u16* __restrict__ dst, int n8, float scale)
{
    const int i = blockIdx.x * 256 + threadIdx.x;
    if (i < n8) *(short8v*)&dst[(size_t)i * 8] = cvt8s(src + (size_t)i * 8, scale);
}

// bias concat: dst[0..1023]=bq*0.125, dst[1024..3071]=bkv
__global__ __launch_bounds__(256) void bias_concat(
    const float* __restrict__ bq, const float* __restrict__ bkv,
    float* __restrict__ dst)
{
    const int i = blockIdx.x * 256 + threadIdx.x;
    if (i < 3072) dst[i] = (i < 1024) ? bq[i] * 0.125f : bkv[i - 1024];
}

// ---------------------------------------------------------------------------
// Pure-bf16 GEMM (m97 structure, proven): C = A @ B^T + bias.
// ---------------------------------------------------------------------------
template<int OF32>
__global__ __launch_bounds__(256, 2) void gemm_bt16(
    const u16* __restrict__ Ap, const u16* __restrict__ Bw,
    const float* __restrict__ bias, void* __restrict__ Cp,
    int M, int N, int K)
{
    __shared__ __align__(16) u16 As[128 * 32];
    __shared__ __align__(16) u16 Bs[128 * 32];
    const int tid  = threadIdx.x;
    const int wave = tid >> 6, lane = tid & 63;
    const int l15  = lane & 15, l4 = lane >> 4;
    const int row0 = blockIdx.x * 128, col0 = blockIdx.y * 128;
    const int wm = (wave >> 1) * 64, wn = (wave & 1) * 64;

    f32x4 acc[4][4];
    #pragma unroll
    for (int i = 0; i < 4; ++i)
        #pragma unroll
        for (int j = 0; j < 4; ++j) acc[i][j] = (f32x4)0.f;

    const int ar = lane >> 2, ac = lane & 3;

    for (int kt = 0; kt < K; kt += 32) {
        __syncthreads();
        #pragma unroll
        for (int i = 0; i < 2; ++i) {
            const int slab = wave * 32 + i * 16;
            const u16* ga = Ap + (size_t)(row0 + slab + ar) * K + kt + ac * 8;
            const u16* gb = Bw + (size_t)(col0 + slab + ar) * K + kt + ac * 8;
            __builtin_amdgcn_global_load_lds(
                (const __attribute__((address_space(1))) unsigned int*)ga,
                (__attribute__((address_space(3))) unsigned int*)&As[slab * 32], 16, 0, 0);
            __builtin_amdgcn_global_load_lds(
                (const __attribute__((address_space(1))) unsigned int*)gb,
                (__attribute__((address_space(3))) unsigned int*)&Bs[slab * 32], 16, 0, 0);
        }
        __syncthreads();

        short8v af[4], bf[4];
        #pragma unroll
        for (int i = 0; i < 4; ++i) {
            af[i] = *(const short8v*)&As[(wm + i * 16 + l15) * 32 + l4 * 8];
            bf[i] = *(const short8v*)&Bs[(wn + i * 16 + l15) * 32 + l4 * 8];
        }
        #pragma unroll
        for (int i = 0; i < 4; ++i)
            #pragma unroll
            for (int j = 0; j < 4; ++j)
                acc[i][j] = __builtin_amdgcn_mfma_f32_16x16x32_bf16(af[i], bf[j], acc[i][j], 0, 0, 0);
    }

    #pragma unroll
    for (int i = 0; i < 4; ++i) {
        const int r = row0 + wm + i * 16 + l4 * 4;
        #pragma unroll
        for (int j = 0; j < 4; ++j) {
            const int c = col0 + wn + j * 16 + l15;
            const float bv = bias[c];
            #pragma unroll
            for (int reg = 0; reg < 4; ++reg) {
                const float rv = acc[i][j][reg] + bv;
                if (OF32) ((float*)Cp)[(size_t)(r + reg) * N + c] = rv;
                else      ((u16*)Cp)[(size_t)(r + reg) * N + c]   = f2b(rv);
            }
        }
    }
}

// ---------------------------------------------------------------------------
// V transpose from fused QKV: VT[bi][hi][d][n] = QKV[bi][n][2048 + hi*64 + d]
// ---------------------------------------------------------------------------
#define QKV_LD 3072

__global__ __launch_bounds__(256) void vtrans_kernel(
    const u16* __restrict__ QKV, u16* __restrict__ VT)
{
    const int u    = blockIdx.x * 4 + (threadIdx.x >> 6);
    const int lane = threadIdx.x & 63;
    const int nch  = u & 255;
    const int hi   = (u >> 8) & 15;
    const int bi   = u >> 12;
    const int n0   = nch * 8;

    short8v sv;
    #pragma unroll
    for (int i = 0; i < 8; ++i)
        sv[i] = (short)QKV[((size_t)(bi * 2048 + n0 + i)) * QKV_LD + 2048 + hi * 64 + lane];
    *(short8v*)&VT[((size_t)((bi * 16 + hi) * 64 + lane)) * 2048 + n0] = sv;
}

// ---------------------------------------------------------------------------
// Flash attention (causal), 8-wave paired blocks. Q pre-scaled by 0.125.
// Diagonal-only masking; defer-max (THR=8); lazy l-reduction (epilogue DPP).
// ---------------------------------------------------------------------------
#define ATT_N 2048
#define ATT_D 1024
#define ATT_HD 64

__global__ __launch_bounds__(512, 2) void flash_attn_kernel(
    const u16* __restrict__ QKV, const u16* __restrict__ VT,
    u16* __restrict__ AO)
{
    const int tid  = threadIdx.x;
    const int wave = tid >> 6, lane = tid & 63;
    const int l15  = lane & 15, l4 = lane >> 4;
    const int pidx = blockIdx.x, hi = blockIdx.y, bi = blockIdx.z;
    const int grp  = wave >> 2, wq = wave & 3;

    const int qt  = grp ? pidx : (31 - pidx);
    const int nt  = qt + 1;
    const int ntmax = 32 - pidx;
    const int qr0 = qt * 64 + wq * 16;

    __shared__ __align__(16) u16 Ks[64 * 72];
    __shared__ __align__(16) u16 Vs[64 * 72];
    __shared__ __align__(16) u16 Ps[8][16 * 72];

    const int sr = tid >> 3, sc = tid & 7;
    const size_t kv_base = (size_t)bi * ATT_N * QKV_LD;
    const size_t vt_base = ((size_t)(bi * 16 + hi)) * 64 * ATT_N;

    const u16* qp = QKV + ((size_t)(bi * ATT_N + qr0 + l15)) * QKV_LD + hi * ATT_HD;
    const short8v aq0 = *(const short8v*)(qp + l4 * 8);
    const short8v aq1 = *(const short8v*)(qp + 32 + l4 * 8);

    float mrow[4], lpart[4];
    f32x4 oacc[4];
    #pragma unroll
    for (int r = 0; r < 4; ++r) { mrow[r] = -1e30f; lpart[r] = 0.f; oacc[r] = (f32x4)0.f; }

    for (int t = 0; t < ntmax; ++t) {
        const int kv0 = t * 64;
        const u16* gk = QKV + kv_base + (size_t)(kv0 + sr) * QKV_LD + 1024 + hi * ATT_HD + sc * 8;
        const u16* gv = VT + vt_base + (size_t)sr * ATT_N + kv0 + sc * 8;
        const short8v kv_ = *(const short8v*)gk;
        const short8v vv_ = *(const short8v*)gv;
        __syncthreads();
        *(short8v*)&Ks[sr * 72 + sc * 8] = kv_;
        *(short8v*)&Vs[sr * 72 + sc * 8] = vv_;
        __syncthreads();

        if (t < nt) {
            f32x4 s[4];
            #pragma unroll
            for (int tt = 0; tt < 4; ++tt) {
                s[tt] = (f32x4)0.f;
                const int rb = tt * 16 + l15;
                const short8v bk0 = *(const short8v*)&Ks[rb * 72 + l4 * 8];
                const short8v bk1 = *(const short8v*)&Ks[rb * 72 + 32 + l4 * 8];
                s[tt] = __builtin_amdgcn_mfma_f32_16x16x32_bf16(aq0, bk0, s[tt], 0, 0, 0);
                s[tt] = __builtin_amdgcn_mfma_f32_16x16x32_bf16(aq1, bk1, s[tt], 0, 0, 0);
            }
            float pv[4][4];
            if (t == nt - 1) {                       // diagonal tile: mask
                #pragma unroll
                for (int tt = 0; tt < 4; ++tt)
                    #pragma unroll
                    for (int r = 0; r < 4; ++r) {
                        const int qg = qr0 + l4 * 4 + r;
                        const int kg = kv0 + tt * 16 + l15;
                        pv[tt][r] = (kg <= qg) ? s[tt][r] : -1e30f;
                    }
            } else {                                 // interior tile: unmasked
                #pragma unroll
                for (int tt = 0; tt < 4; ++tt)
                    #pragma unroll
                    for (int r = 0; r < 4; ++r) pv[tt][r] = s[tt][r];
            }
            // row max (DPP) + defer-max decision
            float pmax[4];
            bool need = false;
            #pragma unroll
            for (int r = 0; r < 4; ++r) {
                float v = fmaxf(fmaxf(pv[0][r], pv[1][r]), fmaxf(pv[2][r], pv[3][r]));
                v = row16_max(v);
                pmax[r] = v;
                need |= (v > mrow[r] + 8.f);
            }
            if (__any(need)) {                       // rescale path (rare after warmup)
                #pragma unroll
                for (int r = 0; r < 4; ++r) {
                    const float mnew = fmaxf(mrow[r], pmax[r]);
                    const float sf = __expf(mrow[r] - mnew);
                    mrow[r] = mnew;
                    lpart[r] *= sf;
                    #pragma unroll
                    for (int j = 0; j < 4; ++j) oacc[j][r] *= sf;
                }
            }
            #pragma unroll
            for (int r = 0; r < 4; ++r) {
                float sum = 0.f;
                #pragma unroll
                for (int tt = 0; tt < 4; ++tt) {
                    const float p = __expf(pv[tt][r] - mrow[r]);
                    pv[tt][r] = p;
                    sum += p;
                }
                lpart[r] += sum;                     // per-lane partial; reduce at end
            }
            u16* Pw = &Ps[wave][0];
            #pragma unroll
            for (int tt = 0; tt < 4; ++tt)
                #pragma unroll
                for (int r = 0; r < 4; ++r)
                    Pw[(l4 * 4 + r) * 72 + tt * 16 + l15] = f2b(pv[tt][r]);
            const short8v ap0 = *(const short8v*)&Pw[l15 * 72 + l4 * 8];
            const short8v ap1 = *(const short8v*)&Pw[l15 * 72 + 32 + l4 * 8];
            #pragma unroll
            for (int j = 0; j < 4; ++j) {
                const int rb = j * 16 + l15;
                const short8v bv0 = *(const short8v*)&Vs[rb * 72 + l4 * 8];
                const short8v bv1 = *(const short8v*)&Vs[rb * 72 + 32 + l4 * 8];
                oacc[j] = __builtin_amdgcn_mfma_f32_16x16x32_bf16(ap0, bv0, oacc[j], 0, 0, 0);
                oacc[j] = __builtin_amdgcn_mfma_f32_16x16x32_bf16(ap1, bv1, oacc[j], 0, 0, 0);
            }
        }
    }

    float lrow[4];
    #pragma unroll
    for (int r = 0; r < 4; ++r) lrow[r] = row16_sum(lpart[r]);

    u16* op = AO + ((size_t)(bi * ATT_N + qr0)) * ATT_D + hi * ATT_HD;
    #pragma unroll
    for (int j = 0; j < 4; ++j)
        #pragma unroll
        for (int r = 0; r < 4; ++r)
            op[(size_t)(l4 * 4 + r) * ATT_D + j * 16 + l15] = f2b(oacc[j][r] / lrow[r]);
}

// ---------------------------------------------------------------------------
extern "C" void kernel_launch(void* const* d_in, const int* in_sizes, int n_in,
                              void* d_out, int out_size, void* d_ws, size_t ws_size,
                              hipStream_t stream) {
    const float* x   = (const float*)d_in[0];
    const float* Wq  = (const float*)d_in[1];
    const float* bq  = (const float*)d_in[2];
    const float* Wkv = (const float*)d_in[3];
    const float* bkv = (const float*)d_in[4];
    const float* Wo  = (const float*)d_in[5];
    const float* bo  = (const float*)d_in[6];
    float* out = (float*)d_out;

    // ws layout (40.01MB, proven):
    //   xb 8MB | QKVb 24MB | VTb 8MB | bqkv 12KB
    // overlays: Wqkvb = first 6MB of VTb (dead before vtrans); AOb = xb;
    //           Wob = QKVb start (post-flash).
    u16* xb    = (u16*)d_ws;                        // 8MB
    u16* QKVb  = xb   + (size_t)4096 * 1024;        // 24MB  [4096][3072]
    u16* VTb   = QKVb + (size_t)4096 * 3072;        // 8MB
    float* bqkv = (float*)(VTb + (size_t)4096 * 2048);  // 12KB
    u16* Wqkvb = VTb;                               // 6MB overlay
    u16* Wob   = QKVb;                              // 2MB overlay (post-flash)
    u16* AOb   = xb;

    dim3 blk(256);
    convx_kernel<<<dim3(2048), blk, 0, stream>>>(x,   xb,    4096 * 1024 / 8, 1.0f);
    convx_kernel<<<dim3( 512), blk, 0, stream>>>(Wq,  Wqkvb, 1024 * 1024 / 8, 0.125f);  // fold attn scale
    convx_kernel<<<dim3(1024), blk, 0, stream>>>(Wkv, Wqkvb + (size_t)1024 * 1024, 2048 * 1024 / 8, 1.0f);
    bias_concat<<<dim3(12), blk, 0, stream>>>(bq, bkv, bqkv);
    gemm_bt16<0><<<dim3(32, 24), blk, 0, stream>>>(xb, Wqkvb, bqkv, QKVb, 4096, 3072, 1024);
    vtrans_kernel<<<dim3(2048), blk, 0, stream>>>(QKVb, VTb);
    flash_attn_kernel<<<dim3(16, 16, 2), dim3(512), 0, stream>>>(QKVb, VTb, AOb);
    convx_kernel<<<dim3( 512), blk, 0, stream>>>(Wo, Wob, 1024 * 1024 / 8, 1.0f);
    gemm_bt16<1><<<dim3(32, 8), blk, 0, stream>>>(AOb, Wob, bo, out, 4096, 1024, 1024);
}

// Round 14
// 132.512 us; speedup vs baseline: 1.3642x; 1.0225x over previous
//
#include <hip/hip_runtime.h>
#include <hip/hip_bf16.h>

typedef unsigned short u16;
typedef __attribute__((ext_vector_type(8))) short short8v;   // 8 bf16 = 16B
typedef __attribute__((ext_vector_type(4))) float f32x4;

__device__ inline u16 f2b(float f) {
    __hip_bfloat16 h = __float2bfloat16(f);
    u16 u; __builtin_memcpy(&u, &h, 2); return u;
}
__device__ inline float b2f(u16 u) {
    __hip_bfloat16 h; __builtin_memcpy(&h, &u, 2); return __bfloat162float(h);
}
__device__ inline short8v cvt8s(const float* p, float s) {
    const f32x4 a = *(const f32x4*)p;
    const f32x4 b = *(const f32x4*)(p + 4);
    short8v r;
    #pragma unroll
    for (int e = 0; e < 4; ++e) { r[e] = (short)f2b(a[e] * s); r[4 + e] = (short)f2b(b[e] * s); }
    return r;
}

// DPP lane-permute within rows of 16 (reduction over lane&15)
template<int CTRL>
__device__ inline float dppf(float x) {
    return __int_as_float(__builtin_amdgcn_update_dpp(
        0, __float_as_int(x), CTRL, 0xF, 0xF, true));
}
__device__ inline float row16_max(float v) {
    v = fmaxf(v, dppf<0xB1>(v));
    v = fmaxf(v, dppf<0x4E>(v));
    v = fmaxf(v, dppf<0x124>(v));
    v = fmaxf(v, dppf<0x128>(v));
    return v;
}
__device__ inline float row16_sum(float v) {
    v += dppf<0xB1>(v);
    v += dppf<0x4E>(v);
    v += dppf<0x124>(v);
    v += dppf<0x128>(v);
    return v;
}

// ---------------------------------------------------------------------------
// fp32 -> bf16 converter with fold-in scale (0.125 for Wq is exact in bf16)
// ---------------------------------------------------------------------------
__global__ __launch_bounds__(256) void convx_kernel(
    const float* __restrict__ src, u16* __restrict__ dst, int n8, float scale)
{
    const int i = blockIdx.x * 256 + threadIdx.x;
    if (i < n8) *(short8v*)&dst[(size_t)i * 8] = cvt8s(src + (size_t)i * 8, scale);
}

// bias concat: dst[0..1023]=bq*0.125, dst[1024..3071]=bkv
__global__ __launch_bounds__(256) void bias_concat(
    const float* __restrict__ bq, const float* __restrict__ bkv,
    float* __restrict__ dst)
{
    const int i = blockIdx.x * 256 + threadIdx.x;
    if (i < 3072) dst[i] = (i < 1024) ? bq[i] * 0.125f : bkv[i - 1024];
}

// ---------------------------------------------------------------------------
// Pure-bf16 GEMM (m97 structure, proven): C = A @ B^T + bias.
// ---------------------------------------------------------------------------
template<int OF32>
__global__ __launch_bounds__(256, 2) void gemm_bt16(
    const u16* __restrict__ Ap, const u16* __restrict__ Bw,
    const float* __restrict__ bias, void* __restrict__ Cp,
    int M, int N, int K)
{
    __shared__ __align__(16) u16 As[128 * 32];
    __shared__ __align__(16) u16 Bs[128 * 32];
    const int tid  = threadIdx.x;
    const int wave = tid >> 6, lane = tid & 63;
    const int l15  = lane & 15, l4 = lane >> 4;
    const int row0 = blockIdx.x * 128, col0 = blockIdx.y * 128;
    const int wm = (wave >> 1) * 64, wn = (wave & 1) * 64;

    f32x4 acc[4][4];
    #pragma unroll
    for (int i = 0; i < 4; ++i)
        #pragma unroll
        for (int j = 0; j < 4; ++j) acc[i][j] = (f32x4)0.f;

    const int ar = lane >> 2, ac = lane & 3;

    for (int kt = 0; kt < K; kt += 32) {
        __syncthreads();
        #pragma unroll
        for (int i = 0; i < 2; ++i) {
            const int slab = wave * 32 + i * 16;
            const u16* ga = Ap + (size_t)(row0 + slab + ar) * K + kt + ac * 8;
            const u16* gb = Bw + (size_t)(col0 + slab + ar) * K + kt + ac * 8;
            __builtin_amdgcn_global_load_lds(
                (const __attribute__((address_space(1))) unsigned int*)ga,
                (__attribute__((address_space(3))) unsigned int*)&As[slab * 32], 16, 0, 0);
            __builtin_amdgcn_global_load_lds(
                (const __attribute__((address_space(1))) unsigned int*)gb,
                (__attribute__((address_space(3))) unsigned int*)&Bs[slab * 32], 16, 0, 0);
        }
        __syncthreads();

        short8v af[4], bf[4];
        #pragma unroll
        for (int i = 0; i < 4; ++i) {
            af[i] = *(const short8v*)&As[(wm + i * 16 + l15) * 32 + l4 * 8];
            bf[i] = *(const short8v*)&Bs[(wn + i * 16 + l15) * 32 + l4 * 8];
        }
        #pragma unroll
        for (int i = 0; i < 4; ++i)
            #pragma unroll
            for (int j = 0; j < 4; ++j)
                acc[i][j] = __builtin_amdgcn_mfma_f32_16x16x32_bf16(af[i], bf[j], acc[i][j], 0, 0, 0);
    }

    #pragma unroll
    for (int i = 0; i < 4; ++i) {
        const int r = row0 + wm + i * 16 + l4 * 4;
        #pragma unroll
        for (int j = 0; j < 4; ++j) {
            const int c = col0 + wn + j * 16 + l15;
            const float bv = bias[c];
            #pragma unroll
            for (int reg = 0; reg < 4; ++reg) {
                const float rv = acc[i][j][reg] + bv;
                if (OF32) ((float*)Cp)[(size_t)(r + reg) * N + c] = rv;
                else      ((u16*)Cp)[(size_t)(r + reg) * N + c]   = f2b(rv);
            }
        }
    }
}

// ---------------------------------------------------------------------------
// V transpose from fused QKV: VT[bi][hi][d][n] = QKV[bi][n][2048 + hi*64 + d]
// ---------------------------------------------------------------------------
#define QKV_LD 3072

__global__ __launch_bounds__(256) void vtrans_kernel(
    const u16* __restrict__ QKV, u16* __restrict__ VT)
{
    const int u    = blockIdx.x * 4 + (threadIdx.x >> 6);
    const int lane = threadIdx.x & 63;
    const int nch  = u & 255;
    const int hi   = (u >> 8) & 15;
    const int bi   = u >> 12;
    const int n0   = nch * 8;

    short8v sv;
    #pragma unroll
    for (int i = 0; i < 8; ++i)
        sv[i] = (short)QKV[((size_t)(bi * 2048 + n0 + i)) * QKV_LD + 2048 + hi * 64 + lane];
    *(short8v*)&VT[((size_t)((bi * 16 + hi) * 64 + lane)) * 2048 + n0] = sv;
}

// ---------------------------------------------------------------------------
// Flash attention (causal), 8-wave paired blocks. Q pre-scaled by 0.125.
// Round-14: double-buffered K/V, ONE barrier/tile, async next-tile loads;
// P-store chunk-XOR swizzle (conflict-free); diag-only mask; defer-max.
// ---------------------------------------------------------------------------
#define ATT_N 2048
#define ATT_D 1024
#define ATT_HD 64

__global__ __launch_bounds__(512, 2) void flash_attn_kernel(
    const u16* __restrict__ QKV, const u16* __restrict__ VT,
    u16* __restrict__ AO)
{
    const int tid  = threadIdx.x;
    const int wave = tid >> 6, lane = tid & 63;
    const int l15  = lane & 15, l4 = lane >> 4;
    const int pidx = blockIdx.x, hi = blockIdx.y, bi = blockIdx.z;
    const int grp  = wave >> 2, wq = wave & 3;

    const int qt  = grp ? pidx : (31 - pidx);
    const int nt  = qt + 1;
    const int ntmax = 32 - pidx;
    const int qr0 = qt * 64 + wq * 16;

    __shared__ __align__(16) u16 Ks[2][64 * 72];
    __shared__ __align__(16) u16 Vs[2][64 * 72];
    __shared__ __align__(16) u16 Ps[8][16 * 72];

    const int sr = tid >> 3, sc = tid & 7;
    const int stoff = sr * 72 + sc * 8;
    const size_t kv_base = (size_t)bi * ATT_N * QKV_LD;
    const size_t vt_base = ((size_t)(bi * 16 + hi)) * 64 * ATT_N;
    const u16* gkb = QKV + kv_base + (size_t)sr * QKV_LD + 1024 + hi * ATT_HD + sc * 8;
    const u16* gvb = VT + vt_base + (size_t)sr * ATT_N + sc * 8;

    const u16* qp = QKV + ((size_t)(bi * ATT_N + qr0 + l15)) * QKV_LD + hi * ATT_HD;
    const short8v aq0 = *(const short8v*)(qp + l4 * 8);
    const short8v aq1 = *(const short8v*)(qp + 32 + l4 * 8);

    float mrow[4], lpart[4];
    f32x4 oacc[4];
    #pragma unroll
    for (int r = 0; r < 4; ++r) { mrow[r] = -1e30f; lpart[r] = 0.f; oacc[r] = (f32x4)0.f; }

    // prologue: stage tile 0 into buffer 0
    *(short8v*)&Ks[0][stoff] = *(const short8v*)gkb;
    *(short8v*)&Vs[0][stoff] = *(const short8v*)gvb;

    short8v kreg, vreg;
    for (int t = 0; t < ntmax; ++t) {
        const int cur = t & 1;
        if (t + 1 < ntmax) {                    // issue next-tile loads (async)
            kreg = *(const short8v*)(gkb + (size_t)(t + 1) * 64 * QKV_LD);
            vreg = *(const short8v*)(gvb + (t + 1) * 64);
        }
        __syncthreads();                        // buf[cur] ready for all waves

        if (t < nt) {
            const int kv0 = t * 64;
            const u16* Kc = &Ks[cur][0];
            const u16* Vc = &Vs[cur][0];
            f32x4 s[4];
            #pragma unroll
            for (int tt = 0; tt < 4; ++tt) {
                s[tt] = (f32x4)0.f;
                const int rb = tt * 16 + l15;
                const short8v bk0 = *(const short8v*)&Kc[rb * 72 + l4 * 8];
                const short8v bk1 = *(const short8v*)&Kc[rb * 72 + 32 + l4 * 8];
                s[tt] = __builtin_amdgcn_mfma_f32_16x16x32_bf16(aq0, bk0, s[tt], 0, 0, 0);
                s[tt] = __builtin_amdgcn_mfma_f32_16x16x32_bf16(aq1, bk1, s[tt], 0, 0, 0);
            }
            float pv[4][4];
            if (t == nt - 1) {                  // diagonal tile: mask
                #pragma unroll
                for (int tt = 0; tt < 4; ++tt)
                    #pragma unroll
                    for (int r = 0; r < 4; ++r) {
                        const int qg = qr0 + l4 * 4 + r;
                        const int kg = kv0 + tt * 16 + l15;
                        pv[tt][r] = (kg <= qg) ? s[tt][r] : -1e30f;
                    }
            } else {
                #pragma unroll
                for (int tt = 0; tt < 4; ++tt)
                    #pragma unroll
                    for (int r = 0; r < 4; ++r) pv[tt][r] = s[tt][r];
            }
            // row max (DPP) + defer-max
            float pmax[4];
            bool need = false;
            #pragma unroll
            for (int r = 0; r < 4; ++r) {
                float v = fmaxf(fmaxf(pv[0][r], pv[1][r]), fmaxf(pv[2][r], pv[3][r]));
                v = row16_max(v);
                pmax[r] = v;
                need |= (v > mrow[r] + 8.f);
            }
            if (__any(need)) {
                #pragma unroll
                for (int r = 0; r < 4; ++r) {
                    const float mnew = fmaxf(mrow[r], pmax[r]);
                    const float sf = __expf(mrow[r] - mnew);
                    mrow[r] = mnew;
                    lpart[r] *= sf;
                    #pragma unroll
                    for (int j = 0; j < 4; ++j) oacc[j][r] *= sf;
                }
            }
            #pragma unroll
            for (int r = 0; r < 4; ++r) {
                float sum = 0.f;
                #pragma unroll
                for (int tt = 0; tt < 4; ++tt) {
                    const float p = __expf(pv[tt][r] - mrow[r]);
                    pv[tt][r] = p;
                    sum += p;
                }
                lpart[r] += sum;
            }
            // P -> LDS, chunk-XOR swizzled: row q, chunk (k>>3)^(q>>2), elem k&7
            u16* Pw = &Ps[wave][0];
            const int h8 = l15 >> 3, e7 = l15 & 7;
            #pragma unroll
            for (int tt = 0; tt < 4; ++tt) {
                const int cc = (((tt << 1) | h8) ^ l4) * 8 + e7;
                #pragma unroll
                for (int r = 0; r < 4; ++r)
                    Pw[(l4 * 4 + r) * 72 + cc] = f2b(pv[tt][r]);
            }
            const int cs = (l4 ^ ((l15 >> 2) & 3)) * 8;
            const short8v ap0 = *(const short8v*)&Pw[l15 * 72 + cs];
            const short8v ap1 = *(const short8v*)&Pw[l15 * 72 + cs + 32];
            #pragma unroll
            for (int j = 0; j < 4; ++j) {
                const int rb = j * 16 + l15;
                const short8v bv0 = *(const short8v*)&Vc[rb * 72 + l4 * 8];
                const short8v bv1 = *(const short8v*)&Vc[rb * 72 + 32 + l4 * 8];
                oacc[j] = __builtin_amdgcn_mfma_f32_16x16x32_bf16(ap0, bv0, oacc[j], 0, 0, 0);
                oacc[j] = __builtin_amdgcn_mfma_f32_16x16x32_bf16(ap1, bv1, oacc[j], 0, 0, 0);
            }
        }

        if (t + 1 < ntmax) {                    // write next tile (vmcnt waits here)
            *(short8v*)&Ks[cur ^ 1][stoff] = kreg;
            *(short8v*)&Vs[cur ^ 1][stoff] = vreg;
        }
    }

    float lrow[4];
    #pragma unroll
    for (int r = 0; r < 4; ++r) lrow[r] = row16_sum(lpart[r]);

    u16* op = AO + ((size_t)(bi * ATT_N + qr0)) * ATT_D + hi * ATT_HD;
    #pragma unroll
    for (int j = 0; j < 4; ++j)
        #pragma unroll
        for (int r = 0; r < 4; ++r)
            op[(size_t)(l4 * 4 + r) * ATT_D + j * 16 + l15] = f2b(oacc[j][r] / lrow[r]);
}

// ---------------------------------------------------------------------------
extern "C" void kernel_launch(void* const* d_in, const int* in_sizes, int n_in,
                              void* d_out, int out_size, void* d_ws, size_t ws_size,
                              hipStream_t stream) {
    const float* x   = (const float*)d_in[0];
    const float* Wq  = (const float*)d_in[1];
    const float* bq  = (const float*)d_in[2];
    const float* Wkv = (const float*)d_in[3];
    const float* bkv = (const float*)d_in[4];
    const float* Wo  = (const float*)d_in[5];
    const float* bo  = (const float*)d_in[6];
    float* out = (float*)d_out;

    // ws layout (40.01MB, proven):
    //   xb 8MB | QKVb 24MB | VTb 8MB | bqkv 12KB
    // overlays: Wqkvb = first 6MB of VTb (dead before vtrans); AOb = xb;
    //           Wob = QKVb start (post-flash).
    u16* xb    = (u16*)d_ws;                        // 8MB
    u16* QKVb  = xb   + (size_t)4096 * 1024;        // 24MB  [4096][3072]
    u16* VTb   = QKVb + (size_t)4096 * 3072;        // 8MB
    float* bqkv = (float*)(VTb + (size_t)4096 * 2048);  // 12KB
    u16* Wqkvb = VTb;                               // 6MB overlay
    u16* Wob   = QKVb;                              // 2MB overlay (post-flash)
    u16* AOb   = xb;

    dim3 blk(256);
    convx_kernel<<<dim3(2048), blk, 0, stream>>>(x,   xb,    4096 * 1024 / 8, 1.0f);
    convx_kernel<<<dim3( 512), blk, 0, stream>>>(Wq,  Wqkvb, 1024 * 1024 / 8, 0.125f);  // fold attn scale
    convx_kernel<<<dim3(1024), blk, 0, stream>>>(Wkv, Wqkvb + (size_t)1024 * 1024, 2048 * 1024 / 8, 1.0f);
    bias_concat<<<dim3(12), blk, 0, stream>>>(bq, bkv, bqkv);
    gemm_bt16<0><<<dim3(32, 24), blk, 0, stream>>>(xb, Wqkvb, bqkv, QKVb, 4096, 3072, 1024);
    vtrans_kernel<<<dim3(2048), blk, 0, stream>>>(QKVb, VTb);
    flash_attn_kernel<<<dim3(16, 16, 2), dim3(512), 0, stream>>>(QKVb, VTb, AOb);
    convx_kernel<<<dim3( 512), blk, 0, stream>>>(Wo, Wob, 1024 * 1024 / 8, 1.0f);
    gemm_bt16<1><<<dim3(32, 8), blk, 0, stream>>>(AOb, Wob, bo, out, 4096, 1024, 1024);
}